// Round 1
// baseline (678.862 us; speedup 1.0000x reference)
//
#include <hip/hip_runtime.h>
#include <hip/hip_fp16.h>

#define S_DIM 2048
#define B_DIM 32
#define E_DIM 1024
#define A_DIM 1024
#define D_DIM 1024
#define M_DIM (S_DIM * B_DIM)  // 65536

typedef _Float16 f16x8 __attribute__((ext_vector_type(8)));
typedef _Float16 f16x4 __attribute__((ext_vector_type(4)));
typedef float f32x4 __attribute__((ext_vector_type(4)));

#define OFF_ENC 0ull
#define OFF_WT  134217728ull
#define OFF_DP  (OFF_WT + 2097152ull)
#define OFF_EN  (OFF_DP + 131072ull)

__device__ inline void load_lds16(const void* g, void* l) {
    __builtin_amdgcn_global_load_lds((const __attribute__((address_space(1))) void*)g,
                                     (__attribute__((address_space(3))) void*)l, 16, 0, 0);
}

__global__ void convert_enc_kernel(const float4* __restrict__ in, f16x4* __restrict__ out) {
    int idx = blockIdx.x * 256 + threadIdx.x;
    float4 f = in[idx];
    f16x4 o = { (_Float16)f.x, (_Float16)f.y, (_Float16)f.z, (_Float16)f.w };
    out[idx] = o;
}

__global__ void transpose_wenc_kernel(const float* __restrict__ W, _Float16* __restrict__ WT) {
    __shared__ _Float16 tile[32][33];
    int a0 = blockIdx.x * 32, e0 = blockIdx.y * 32;
    int tx = threadIdx.x & 31, ty = threadIdx.x >> 5;
    #pragma unroll
    for (int i = 0; i < 32; i += 8)
        tile[ty + i][tx] = (_Float16)W[(size_t)(e0 + ty + i) * A_DIM + a0 + tx];
    __syncthreads();
    #pragma unroll
    for (int i = 0; i < 32; i += 8)
        WT[(size_t)(a0 + ty + i) * E_DIM + e0 + tx] = tile[tx][ty + i];
}

__global__ void decproj_kernel(const float* __restrict__ dec, const float* __restrict__ Wd,
                               const float* __restrict__ bias, float* __restrict__ dp) {
    int a = blockIdx.x * 256 + threadIdx.x;
    int b = blockIdx.y;
    float acc = bias[a];
    const float* dr = dec + (size_t)b * D_DIM;
    const float* wcol = Wd + a;
    #pragma unroll 8
    for (int d = 0; d < D_DIM; ++d)
        acc += dr[d] * wcol[(size_t)d * A_DIM];
    dp[(size_t)b * A_DIM + a] = acc;
}

// 256x256 tile, BK=64, 8 waves (2M x 4N, 128x64 per wave), double-buffered LDS
// (128 KiB), counted vmcnt(8) so a full K-tile of loads stays in flight across
// the barriers (T3+T4), setprio around MFMA clusters (T5).
// LDS is linear (global_load_lds writes base+lane*16); bank-conflict swizzle is
// achieved by XOR-permuting the GLOBAL source chunk (lane&7)^(lane>>3) and
// applying the same XOR on the ds_read slot (both-sides-or-neither).
__global__ __launch_bounds__(512, 2)
void energy_gemm_kernel(const _Float16* __restrict__ Af, const _Float16* __restrict__ Bt,
                        const float* __restrict__ dp, const float* __restrict__ v,
                        float* __restrict__ energy) {
    __shared__ alignas(16) _Float16 Atile[2][256 * 64];
    __shared__ alignas(16) _Float16 Btile[2][256 * 64];

    const int tid = threadIdx.x;
    const int wid = tid >> 6;
    const int lane = tid & 63;
    const int quad = lane >> 4;
    const int l15 = lane & 15;
    const int l7 = l15 & 7;

    // grid = 1024 blocks = 256 m-tiles x 4 n-tiles; 1024 % 8 == 0 so the
    // mod-8 XCD swizzle is bijective. Each XCD owns 32 contiguous m-tiles
    // with all 4 n-tiles -> A panel re-read 4x, mostly L2-resident.
    const int bid = blockIdx.x;
    const int xcd = bid & 7;
    const int local = bid >> 3;                 // 0..127
    const int m0 = (xcd * 32 + (local >> 2)) * 256;
    const int n0 = (local & 3) * 256;

    const int wm = (wid >> 2) * 128;            // 0 / 128
    const int wn = (wid & 3) * 64;              // 0..192

    // staging: per K-tile each wave issues 4 A + 4 B global_load_lds (1 KB
    // each = 8 rows x 128 B). lane covers row (lane>>3), phys slot (lane&7);
    // fetch the global 16B chunk (lane&7)^(lane>>3) so that physical slot s of
    // row r holds logical chunk s^(r&7).
    const int lr = lane >> 3;
    const int lcol = ((lane & 7) ^ lr) * 8;
    const int srow = wid * 8;
    const _Float16* Ag = Af + (size_t)(m0 + srow + lr) * E_DIM + lcol;
    const _Float16* Bg = Bt + (size_t)(n0 + srow + lr) * E_DIM + lcol;

#define STAGE(bufi, k0)                                                       \
    {                                                                         \
        _Float16* ad = &Atile[bufi][srow * 64];                               \
        _Float16* bd = &Btile[bufi][srow * 64];                               \
        _Pragma("unroll")                                                     \
        for (int p = 0; p < 4; ++p) {                                         \
            load_lds16(Ag + (size_t)p * 64 * E_DIM + (k0), ad + p * 4096);    \
            load_lds16(Bg + (size_t)p * 64 * E_DIM + (k0), bd + p * 4096);    \
        }                                                                     \
    }

    f32x4 acc[8][4] = {};

    STAGE(0, 0)
    STAGE(1, 64)

    for (int t = 0; t < 16; ++t) {
        const int buf = t & 1;
        // tile t's 8 loads are complete; tile t+1's 8 may remain in flight.
        if (t == 15) asm volatile("s_waitcnt vmcnt(0)" ::: "memory");
        else         asm volatile("s_waitcnt vmcnt(8)" ::: "memory");
        __builtin_amdgcn_s_barrier();
        asm volatile("" ::: "memory");

        #pragma unroll
        for (int kh = 0; kh < 2; ++kh) {
            f16x8 bf[4];
            #pragma unroll
            for (int j = 0; j < 4; ++j) {
                const int row = wn + j * 16 + l15;
                const int slot = (quad + kh * 4) ^ l7;
                bf[j] = *(const f16x8*)&Btile[buf][row * 64 + slot * 8];
            }
            #pragma unroll
            for (int mh = 0; mh < 2; ++mh) {
                f16x8 af[4];
                #pragma unroll
                for (int i = 0; i < 4; ++i) {
                    const int row = wm + mh * 64 + i * 16 + l15;
                    const int slot = (quad + kh * 4) ^ l7;
                    af[i] = *(const f16x8*)&Atile[buf][row * 64 + slot * 8];
                }
                __builtin_amdgcn_s_setprio(1);
                #pragma unroll
                for (int i = 0; i < 4; ++i)
                    #pragma unroll
                    for (int j = 0; j < 4; ++j)
                        acc[mh * 4 + i][j] = __builtin_amdgcn_mfma_f32_16x16x32_f16(
                            af[i], bf[j], acc[mh * 4 + i][j], 0, 0, 0);
                __builtin_amdgcn_s_setprio(0);
            }
        }

        asm volatile("" ::: "memory");
        __builtin_amdgcn_s_barrier();
        asm volatile("" ::: "memory");
        // all waves are past the reads of buf -> refill it for tile t+2;
        // these loads get ~2 full tile-computes to land.
        if (t + 2 < 16) STAGE(buf, (t + 2) * 64)
    }
#undef STAGE

    float vf[4];
    #pragma unroll
    for (int j = 0; j < 4; ++j) vf[j] = v[n0 + wn + j * 16 + l15];

    #pragma unroll
    for (int i = 0; i < 8; ++i) {
        #pragma unroll
        for (int r = 0; r < 4; ++r) {
            int m = m0 + wm + i * 16 + quad * 4 + r;   // m = s*32 + b
            int bidx = m & 31;
            float sum = 0.f;
            #pragma unroll
            for (int j = 0; j < 4; ++j) {
                int a = n0 + wn + j * 16 + l15;
                float x = acc[i][j][r] + dp[bidx * A_DIM + a];
                float ex = __expf(2.f * x);
                float th = 1.f - 2.f * __builtin_amdgcn_rcpf(ex + 1.f);
                sum += th * vf[j];
            }
            sum += __shfl_xor(sum, 1);
            sum += __shfl_xor(sum, 2);
            sum += __shfl_xor(sum, 4);
            sum += __shfl_xor(sum, 8);
            if (l15 == 0) atomicAdd(&energy[bidx * S_DIM + (m >> 5)], sum);
        }
    }
}

// one block per b column; energy [B][S] coalesced; noise [S][B] added here
__global__ void scan_alpha_kernel(const float* __restrict__ energy, const float* __restrict__ noise,
                                  float* __restrict__ alpha) {
    __shared__ float sc[256];
    __shared__ float red[256];
    const int b = blockIdx.x;
    const int t = threadIdx.x;
    float p[8], q[8];
    float prod = 1.f;
    #pragma unroll
    for (int k = 0; k < 8; ++k) {
        int s = t * 8 + k;
        float x = energy[b * S_DIM + s] + noise[s * B_DIM + b];
        p[k] = __builtin_amdgcn_rcpf(1.f + __expf(-x));
        q[k] = __builtin_amdgcn_rcpf(1.f + __expf(x));
        prod *= q[k];
    }
    sc[t] = prod;
    __syncthreads();
    for (int off = 1; off < 256; off <<= 1) {
        float mine = sc[t];
        float other = (t >= off) ? sc[t - off] : 1.f;
        __syncthreads();
        sc[t] = mine * other;
        __syncthreads();
    }
    float run = (t > 0) ? sc[t - 1] : 1.f;
    float lsum = 0.f;
    #pragma unroll
    for (int k = 0; k < 8; ++k) {
        int s = t * 8 + k;
        float al = p[k] * run;
        run *= q[k];
        if (s < S_DIM - 1) { alpha[s * B_DIM + b] = al; lsum += al; }
    }
    red[t] = lsum;
    __syncthreads();
    for (int off = 128; off > 0; off >>= 1) {
        if (t < off) red[t] += red[t + off];
        __syncthreads();
    }
    if (t == 0) {
        float tot = fminf(fmaxf(red[0], 0.f), 1.f);
        alpha[(S_DIM - 1) * B_DIM + b] = 1.f - tot;
    }
}

// grid (16 s-chunks, 32 b), block 256: thread t covers e = (t&127)*8..+7 (16B loads),
// halves t<128 / t>=128 split the s range, LDS-reduce, one atomic set per block.
__global__ void wc_kernel(const _Float16* __restrict__ enc, const float* __restrict__ alpha,
                          float* __restrict__ wc) {
    __shared__ float red[128][8];
    const int b = blockIdx.y;
    const int t = threadIdx.x;
    const int e0 = (t & 127) * 8;
    const int half = t >> 7;
    int s = blockIdx.x * 128 + half;
    float acc[8] = {};
    for (int i = 0; i < 64; ++i, s += 2) {
        float al = alpha[s * B_DIM + b];
        f16x8 r = *(const f16x8*)&enc[((size_t)s * B_DIM + b) * E_DIM + e0];
        #pragma unroll
        for (int k = 0; k < 8; ++k) acc[k] += al * (float)r[k];
    }
    if (half) {
        #pragma unroll
        for (int k = 0; k < 8; ++k) red[t - 128][k] = acc[k];
    }
    __syncthreads();
    if (!half) {
        #pragma unroll
        for (int k = 0; k < 8; ++k)
            atomicAdd(&wc[b * E_DIM + e0 + k], acc[k] + red[t][k]);
    }
}

extern "C" void kernel_launch(void* const* d_in, const int* in_sizes, int n_in,
                              void* d_out, int out_size, void* d_ws, size_t ws_size,
                              hipStream_t stream) {
    const float* dec   = (const float*)d_in[0];
    const float* enc   = (const float*)d_in[1];
    const float* noise = (const float*)d_in[2];
    const float* Wd    = (const float*)d_in[3];
    const float* We    = (const float*)d_in[4];
    const float* bias  = (const float*)d_in[5];
    const float* v     = (const float*)d_in[6];

    char* ws = (char*)d_ws;
    _Float16* encf = (_Float16*)(ws + OFF_ENC);
    _Float16* wtf  = (_Float16*)(ws + OFF_WT);
    float* dp      = (float*)(ws + OFF_DP);
    float* energy  = (float*)(ws + OFF_EN);

    float* wc    = (float*)d_out;
    float* alpha = (float*)d_out + B_DIM * E_DIM;

    (void)hipMemsetAsync(wc, 0, B_DIM * E_DIM * sizeof(float), stream);
    (void)hipMemsetAsync(energy, 0, M_DIM * sizeof(float), stream);

    convert_enc_kernel<<<dim3(M_DIM * E_DIM / 4 / 256), 256, 0, stream>>>((const float4*)enc, (f16x4*)encf);
    transpose_wenc_kernel<<<dim3(32, 32), 256, 0, stream>>>(We, wtf);
    decproj_kernel<<<dim3(4, 32), 256, 0, stream>>>(dec, Wd, bias, dp);
    energy_gemm_kernel<<<dim3(1024), 512, 0, stream>>>(encf, wtf, dp, v, energy);
    scan_alpha_kernel<<<dim3(32), 256, 0, stream>>>(energy, noise, alpha);
    wc_kernel<<<dim3(16, 32), 256, 0, stream>>>(encf, alpha, wc);
}

// Round 2
// 668.957 us; speedup vs baseline: 1.0148x; 1.0148x over previous
//
#include <hip/hip_runtime.h>
#include <hip/hip_fp16.h>

#define S_DIM 2048
#define B_DIM 32
#define E_DIM 1024
#define A_DIM 1024
#define D_DIM 1024
#define M_DIM (S_DIM * B_DIM)  // 65536

typedef _Float16 f16x8 __attribute__((ext_vector_type(8)));
typedef _Float16 f16x4 __attribute__((ext_vector_type(4)));
typedef float f32x4 __attribute__((ext_vector_type(4)));

#define OFF_ENC 0ull
#define OFF_WT  134217728ull
#define OFF_DP  (OFF_WT + 2097152ull)
#define OFF_EN  (OFF_DP + 131072ull)

__device__ inline void load_lds16(const void* g, void* l) {
    __builtin_amdgcn_global_load_lds((const __attribute__((address_space(1))) void*)g,
                                     (__attribute__((address_space(3))) void*)l, 16, 0, 0);
}

__global__ void convert_enc_kernel(const float4* __restrict__ in, f16x4* __restrict__ out) {
    int idx = blockIdx.x * 256 + threadIdx.x;
    float4 f = in[idx];
    f16x4 o = { (_Float16)f.x, (_Float16)f.y, (_Float16)f.z, (_Float16)f.w };
    out[idx] = o;
}

__global__ void transpose_wenc_kernel(const float* __restrict__ W, _Float16* __restrict__ WT) {
    __shared__ _Float16 tile[32][33];
    int a0 = blockIdx.x * 32, e0 = blockIdx.y * 32;
    int tx = threadIdx.x & 31, ty = threadIdx.x >> 5;
    #pragma unroll
    for (int i = 0; i < 32; i += 8)
        tile[ty + i][tx] = (_Float16)W[(size_t)(e0 + ty + i) * A_DIM + a0 + tx];
    __syncthreads();
    #pragma unroll
    for (int i = 0; i < 32; i += 8)
        WT[(size_t)(a0 + ty + i) * E_DIM + e0 + tx] = tile[tx][ty + i];
}

__global__ void decproj_kernel(const float* __restrict__ dec, const float* __restrict__ Wd,
                               const float* __restrict__ bias, float* __restrict__ dp) {
    int a = blockIdx.x * 256 + threadIdx.x;
    int b = blockIdx.y;
    float acc = bias[a];
    const float* dr = dec + (size_t)b * D_DIM;
    const float* wcol = Wd + a;
    #pragma unroll 8
    for (int d = 0; d < D_DIM; ++d)
        acc += dr[d] * wcol[(size_t)d * A_DIM];
    dp[(size_t)b * A_DIM + a] = acc;
}

// 256x256 tile, BK=32, 8 waves (2M x 4N, 128x64 per wave).
// 4-deep LDS tile ring (As[4]/Bs[4], 128 KiB): while computing tile t, stage
// tile t+3 into slot (t+3)&3 = tile t-1's slot (fully consumed -> no race).
// K-loop fully unrolled so every slot index is a compile-time constant
// (lets the compiler prove ds_read vs global_load_lds disjointness -> no
// spurious vmcnt drains). 2 phases/tile, 16 MFMA per barrier-pair (template
// rhythm, m196/m201), counted vmcnt(8) at tile end (never 0 in steady state),
// setprio(1) around MFMA clusters. Linear LDS: 64 B rows at BK=32 spread a
// b128 fragment read across all 32 banks at 2-way (free) -> no swizzle.
__global__ __launch_bounds__(512, 2)
void energy_gemm_kernel(const _Float16* __restrict__ Af, const _Float16* __restrict__ Bt,
                        const float* __restrict__ dp, const float* __restrict__ v,
                        float* __restrict__ energy) {
    __shared__ alignas(16) _Float16 As[4][256 * 32];
    __shared__ alignas(16) _Float16 Bs[4][256 * 32];

    const int tid = threadIdx.x;
    const int wid = tid >> 6;
    const int lane = tid & 63;
    const int quad = lane >> 4;
    const int l15 = lane & 15;

    // grid = 1024 blocks = 256 m-tiles x 4 n-tiles; bid%8 = XCD (bijective,
    // 1024%8==0). Concurrent window per XCD = 32 blocks = 8 m-tiles x 4 n
    // -> A working set ~4MB ~ L2.
    const int bid = blockIdx.x;
    const int xcd = bid & 7;
    const int local = bid >> 3;                 // 0..127
    const int m0 = (xcd * 32 + (local >> 2)) * 256;
    const int n0 = (local & 3) * 256;

    const int wm = (wid >> 2) * 128;            // 0 / 128
    const int wn = (wid & 3) * 64;              // 0..192

    // staging: wave wid covers row-segments wid (rows wid*16..+15) and wid+8
    // (rows 128+wid*16..). lane l -> row seg*16 + (l>>2), 16B chunk l&3.
    // LDS dest (wave-uniform base + lane*16) lands exactly at linear [row][32].
    const int lr = lane >> 2;
    const int lc = (lane & 3) * 8;
    const _Float16* Ag = Af + (size_t)(m0 + wid * 16 + lr) * E_DIM + lc;
    const _Float16* Bg = Bt + (size_t)(n0 + wid * 16 + lr) * E_DIM + lc;

#define STAGE_A(u)                                                              \
    {                                                                           \
        load_lds16(Ag + (size_t)(u) * 32, &As[(u) & 3][wid * 512]);             \
        load_lds16(Ag + (size_t)128 * E_DIM + (size_t)(u) * 32,                 \
                   &As[(u) & 3][(wid + 8) * 512]);                              \
    }
#define STAGE_B(u)                                                              \
    {                                                                           \
        load_lds16(Bg + (size_t)(u) * 32, &Bs[(u) & 3][wid * 512]);             \
        load_lds16(Bg + (size_t)128 * E_DIM + (size_t)(u) * 32,                 \
                   &Bs[(u) & 3][(wid + 8) * 512]);                              \
    }

    f32x4 acc[8][4] = {};

    // prologue: tiles 0,1,2 staged (12 loads); vmcnt(8) -> tile 0 complete.
    STAGE_A(0) STAGE_B(0)
    STAGE_A(1) STAGE_B(1)
    STAGE_A(2) STAGE_B(2)
    asm volatile("s_waitcnt vmcnt(8)" ::: "memory");
    __builtin_amdgcn_s_barrier();
    asm volatile("" ::: "memory");

    #pragma unroll
    for (int t = 0; t < 32; ++t) {
        const int slot = t & 3;
        f16x8 af[4], bf[4];

        // ---- phase 0: rows wm..wm+63 (acc[0..3]) ----
        #pragma unroll
        for (int j = 0; j < 4; ++j)
            bf[j] = *(const f16x8*)&Bs[slot][(wn + j * 16 + l15) * 32 + quad * 8];
        #pragma unroll
        for (int i = 0; i < 4; ++i)
            af[i] = *(const f16x8*)&As[slot][(wm + i * 16 + l15) * 32 + quad * 8];
        if (t < 29) STAGE_A(t + 3)
        asm volatile("" ::: "memory");
        __builtin_amdgcn_s_barrier();
        asm volatile("" ::: "memory");
        __builtin_amdgcn_s_setprio(1);
        #pragma unroll
        for (int i = 0; i < 4; ++i)
            #pragma unroll
            for (int j = 0; j < 4; ++j)
                acc[i][j] = __builtin_amdgcn_mfma_f32_16x16x32_f16(af[i], bf[j], acc[i][j], 0, 0, 0);
        __builtin_amdgcn_s_setprio(0);
        asm volatile("" ::: "memory");
        __builtin_amdgcn_s_barrier();
        asm volatile("" ::: "memory");

        // ---- phase 1: rows wm+64..wm+127 (acc[4..7]) ----
        #pragma unroll
        for (int i = 0; i < 4; ++i)
            af[i] = *(const f16x8*)&As[slot][(wm + 64 + i * 16 + l15) * 32 + quad * 8];
        if (t < 29) STAGE_B(t + 3)
        asm volatile("" ::: "memory");
        __builtin_amdgcn_s_barrier();
        asm volatile("" ::: "memory");
        __builtin_amdgcn_s_setprio(1);
        #pragma unroll
        for (int i = 0; i < 4; ++i)
            #pragma unroll
            for (int j = 0; j < 4; ++j)
                acc[4 + i][j] = __builtin_amdgcn_mfma_f32_16x16x32_f16(af[i], bf[j], acc[4 + i][j], 0, 0, 0);
        __builtin_amdgcn_s_setprio(0);
        // end-of-tile counted wait: stages from tiles t and t-1 (8 loads) may
        // stay in flight; tile t+1's data (staged at t-2) is then complete.
        // Tail: t=29 -> only tile-31's 4 loads may fly; t=30 -> drain.
        if (t <= 28)      asm volatile("s_waitcnt vmcnt(8)" ::: "memory");
        else if (t == 29) asm volatile("s_waitcnt vmcnt(4)" ::: "memory");
        else if (t == 30) asm volatile("s_waitcnt vmcnt(0)" ::: "memory");
        asm volatile("" ::: "memory");
        __builtin_amdgcn_s_barrier();
        asm volatile("" ::: "memory");
    }
#undef STAGE_A
#undef STAGE_B

    float vf[4];
    #pragma unroll
    for (int j = 0; j < 4; ++j) vf[j] = v[n0 + wn + j * 16 + l15];

    #pragma unroll
    for (int i = 0; i < 8; ++i) {
        #pragma unroll
        for (int r = 0; r < 4; ++r) {
            int m = m0 + wm + i * 16 + quad * 4 + r;   // m = s*32 + b
            int bidx = m & 31;
            float sum = 0.f;
            #pragma unroll
            for (int j = 0; j < 4; ++j) {
                int a = n0 + wn + j * 16 + l15;
                float x = acc[i][j][r] + dp[bidx * A_DIM + a];
                float ex = __expf(2.f * x);
                float th = 1.f - 2.f * __builtin_amdgcn_rcpf(ex + 1.f);
                sum += th * vf[j];
            }
            sum += __shfl_xor(sum, 1);
            sum += __shfl_xor(sum, 2);
            sum += __shfl_xor(sum, 4);
            sum += __shfl_xor(sum, 8);
            if (l15 == 0) atomicAdd(&energy[bidx * S_DIM + (m >> 5)], sum);
        }
    }
}

// one block per b column; energy [B][S] coalesced; noise [S][B] added here
__global__ void scan_alpha_kernel(const float* __restrict__ energy, const float* __restrict__ noise,
                                  float* __restrict__ alpha) {
    __shared__ float sc[256];
    __shared__ float red[256];
    const int b = blockIdx.x;
    const int t = threadIdx.x;
    float p[8], q[8];
    float prod = 1.f;
    #pragma unroll
    for (int k = 0; k < 8; ++k) {
        int s = t * 8 + k;
        float x = energy[b * S_DIM + s] + noise[s * B_DIM + b];
        p[k] = __builtin_amdgcn_rcpf(1.f + __expf(-x));
        q[k] = __builtin_amdgcn_rcpf(1.f + __expf(x));
        prod *= q[k];
    }
    sc[t] = prod;
    __syncthreads();
    for (int off = 1; off < 256; off <<= 1) {
        float mine = sc[t];
        float other = (t >= off) ? sc[t - off] : 1.f;
        __syncthreads();
        sc[t] = mine * other;
        __syncthreads();
    }
    float run = (t > 0) ? sc[t - 1] : 1.f;
    float lsum = 0.f;
    #pragma unroll
    for (int k = 0; k < 8; ++k) {
        int s = t * 8 + k;
        float al = p[k] * run;
        run *= q[k];
        if (s < S_DIM - 1) { alpha[s * B_DIM + b] = al; lsum += al; }
    }
    red[t] = lsum;
    __syncthreads();
    for (int off = 128; off > 0; off >>= 1) {
        if (t < off) red[t] += red[t + off];
        __syncthreads();
    }
    if (t == 0) {
        float tot = fminf(fmaxf(red[0], 0.f), 1.f);
        alpha[(S_DIM - 1) * B_DIM + b] = 1.f - tot;
    }
}

// grid (16 s-chunks, 32 b), block 256: thread t covers e = (t&127)*8..+7 (16B loads),
// halves t<128 / t>=128 split the s range, LDS-reduce, one atomic set per block.
__global__ void wc_kernel(const _Float16* __restrict__ enc, const float* __restrict__ alpha,
                          float* __restrict__ wc) {
    __shared__ float red[128][8];
    const int b = blockIdx.y;
    const int t = threadIdx.x;
    const int e0 = (t & 127) * 8;
    const int half = t >> 7;
    int s = blockIdx.x * 128 + half;
    float acc[8] = {};
    for (int i = 0; i < 64; ++i, s += 2) {
        float al = alpha[s * B_DIM + b];
        f16x8 r = *(const f16x8*)&enc[((size_t)s * B_DIM + b) * E_DIM + e0];
        #pragma unroll
        for (int k = 0; k < 8; ++k) acc[k] += al * (float)r[k];
    }
    if (half) {
        #pragma unroll
        for (int k = 0; k < 8; ++k) red[t - 128][k] = acc[k];
    }
    __syncthreads();
    if (!half) {
        #pragma unroll
        for (int k = 0; k < 8; ++k)
            atomicAdd(&wc[b * E_DIM + e0 + k], acc[k] + red[t][k]);
    }
}

extern "C" void kernel_launch(void* const* d_in, const int* in_sizes, int n_in,
                              void* d_out, int out_size, void* d_ws, size_t ws_size,
                              hipStream_t stream) {
    const float* dec   = (const float*)d_in[0];
    const float* enc   = (const float*)d_in[1];
    const float* noise = (const float*)d_in[2];
    const float* Wd    = (const float*)d_in[3];
    const float* We    = (const float*)d_in[4];
    const float* bias  = (const float*)d_in[5];
    const float* v     = (const float*)d_in[6];

    char* ws = (char*)d_ws;
    _Float16* encf = (_Float16*)(ws + OFF_ENC);
    _Float16* wtf  = (_Float16*)(ws + OFF_WT);
    float* dp      = (float*)(ws + OFF_DP);
    float* energy  = (float*)(ws + OFF_EN);

    float* wc    = (float*)d_out;
    float* alpha = (float*)d_out + B_DIM * E_DIM;

    (void)hipMemsetAsync(wc, 0, B_DIM * E_DIM * sizeof(float), stream);
    (void)hipMemsetAsync(energy, 0, M_DIM * sizeof(float), stream);

    convert_enc_kernel<<<dim3(M_DIM * E_DIM / 4 / 256), 256, 0, stream>>>((const float4*)enc, (f16x4*)encf);
    transpose_wenc_kernel<<<dim3(32, 32), 256, 0, stream>>>(We, wtf);
    decproj_kernel<<<dim3(4, 32), 256, 0, stream>>>(dec, Wd, bias, dp);
    energy_gemm_kernel<<<dim3(1024), 512, 0, stream>>>(encf, wtf, dp, v, energy);
    scan_alpha_kernel<<<dim3(32), 256, 0, stream>>>(energy, noise, alpha);
    wc_kernel<<<dim3(16, 32), 256, 0, stream>>>(encf, alpha, wc);
}

// Round 3
// 640.068 us; speedup vs baseline: 1.0606x; 1.0451x over previous
//
#include <hip/hip_runtime.h>
#include <hip/hip_fp16.h>

#define S_DIM 2048
#define B_DIM 32
#define E_DIM 1024
#define A_DIM 1024
#define D_DIM 1024
#define M_DIM (S_DIM * B_DIM)  // 65536

typedef _Float16 f16x8 __attribute__((ext_vector_type(8)));
typedef _Float16 f16x4 __attribute__((ext_vector_type(4)));
typedef float f32x4 __attribute__((ext_vector_type(4)));

#define OFF_ENC 0ull
#define OFF_WT  134217728ull
#define OFF_DP  (OFF_WT + 2097152ull)
#define OFF_EN  (OFF_DP + 131072ull)

__device__ inline void load_lds16(const void* g, void* l) {
    __builtin_amdgcn_global_load_lds((const __attribute__((address_space(1))) void*)g,
                                     (__attribute__((address_space(3))) void*)l, 16, 0, 0);
}

__global__ void convert_enc_kernel(const float4* __restrict__ in, f16x4* __restrict__ out) {
    int idx = blockIdx.x * 256 + threadIdx.x;
    float4 f = in[idx];
    f16x4 o = { (_Float16)f.x, (_Float16)f.y, (_Float16)f.z, (_Float16)f.w };
    out[idx] = o;
}

__global__ void transpose_wenc_kernel(const float* __restrict__ W, _Float16* __restrict__ WT) {
    __shared__ _Float16 tile[32][33];
    int a0 = blockIdx.x * 32, e0 = blockIdx.y * 32;
    int tx = threadIdx.x & 31, ty = threadIdx.x >> 5;
    #pragma unroll
    for (int i = 0; i < 32; i += 8)
        tile[ty + i][tx] = (_Float16)W[(size_t)(e0 + ty + i) * A_DIM + a0 + tx];
    __syncthreads();
    #pragma unroll
    for (int i = 0; i < 32; i += 8)
        WT[(size_t)(a0 + ty + i) * E_DIM + e0 + tx] = tile[tx][ty + i];
}

// grid (A/64, 4): block covers 64 a-cols x all 32 b for a 256-wide d-slice.
// Wd is read exactly once across the grid (was 32x). dp must be zeroed first;
// bias added by the d0==0 slice.
__global__ void decproj_kernel(const float* __restrict__ dec, const float* __restrict__ Wd,
                               const float* __restrict__ bias, float* __restrict__ dp) {
    const int t = threadIdx.x;
    const int a = blockIdx.x * 64 + (t & 63);
    const int bg = t >> 6;            // 0..3 -> b = bg*8 + bi
    const int d0 = blockIdx.y * 256;
    float acc[8] = {};
    #pragma unroll 4
    for (int d = d0; d < d0 + 256; ++d) {
        float w = Wd[(size_t)d * A_DIM + a];
        #pragma unroll
        for (int bi = 0; bi < 8; ++bi)
            acc[bi] += dec[(size_t)(bg * 8 + bi) * D_DIM + d] * w;
    }
    #pragma unroll
    for (int bi = 0; bi < 8; ++bi) {
        float add = acc[bi] + (blockIdx.y == 0 ? bias[a] : 0.f);
        atomicAdd(&dp[(size_t)(bg * 8 + bi) * A_DIM + a], add);
    }
}

// 256x256 tile, BK=32, 8 waves (2M x 4N, 128x64 per wave).
// 4-deep LDS tile ring (As[4]/Bs[4], 128 KiB): while computing tile t, stage
// tile t+3 into slot (t+3)&3 = tile t-1's slot (fully consumed -> no race).
// K-loop fully unrolled -> compile-time slot indices -> no spurious vmcnt
// drains. 2 phases/tile, 16 MFMA per barrier-pair, counted vmcnt(8) at tile
// end (never 0 in steady state), setprio(1) around MFMA clusters.
// Bank conflicts: chunk-XOR swizzle (verified 0-conflict in round 0):
// physical 16B chunk p of row r holds logical chunk p^((r>>1)&3); staged by
// XOR-ing the GLOBAL source chunk (LDS dest stays linear for global_load_lds),
// read by XOR-ing the slot. Bank-group = 16*(l15&1)+4*(quad^((l15>>1)&3))
// -> all 8 groups hit exactly 2x per quad-sweep -> 2-way = free (m136).
__global__ __launch_bounds__(512, 2)
void energy_gemm_kernel(const _Float16* __restrict__ Af, const _Float16* __restrict__ Bt,
                        const float* __restrict__ dp, const float* __restrict__ v,
                        float* __restrict__ energy) {
    __shared__ alignas(16) _Float16 As[4][256 * 32];
    __shared__ alignas(16) _Float16 Bs[4][256 * 32];

    const int tid = threadIdx.x;
    const int wid = tid >> 6;
    const int lane = tid & 63;
    const int quad = lane >> 4;
    const int l15 = lane & 15;
    const int rsw = ((l15 >> 1) & 3);   // reader row-XOR term

    // grid = 1024 blocks = 256 m-tiles x 4 n-tiles; bid%8 = XCD (bijective).
    const int bid = blockIdx.x;
    const int xcd = bid & 7;
    const int local = bid >> 3;                 // 0..127
    const int m0 = (xcd * 32 + (local >> 2)) * 256;
    const int n0 = (local & 3) * 256;

    const int wm = (wid >> 2) * 128;            // 0 / 128
    const int wn = (wid & 3) * 64;              // 0..192

    // staging: wave wid covers rows wid*16..+15 and 128+wid*16..+15.
    // lane l -> row base+(l>>2), physical chunk l&3; fetch global chunk
    // (l&3)^((l>>3)&3) (= (l&3)^((row>>1)&3) since base%16==0).
    const int lr = lane >> 2;
    const int lc = ((lane & 3) ^ ((lane >> 3) & 3)) * 8;
    const _Float16* Ag = Af + (size_t)(m0 + wid * 16 + lr) * E_DIM + lc;
    const _Float16* Bg = Bt + (size_t)(n0 + wid * 16 + lr) * E_DIM + lc;

#define STAGE_A(u)                                                              \
    {                                                                           \
        load_lds16(Ag + (size_t)(u) * 32, &As[(u) & 3][wid * 512]);             \
        load_lds16(Ag + (size_t)128 * E_DIM + (size_t)(u) * 32,                 \
                   &As[(u) & 3][(wid + 8) * 512]);                              \
    }
#define STAGE_B(u)                                                              \
    {                                                                           \
        load_lds16(Bg + (size_t)(u) * 32, &Bs[(u) & 3][wid * 512]);             \
        load_lds16(Bg + (size_t)128 * E_DIM + (size_t)(u) * 32,                 \
                   &Bs[(u) & 3][(wid + 8) * 512]);                              \
    }

    f32x4 acc[8][4] = {};

    // prologue: tiles 0,1,2 staged (12 loads); vmcnt(8) -> tile 0 complete.
    STAGE_A(0) STAGE_B(0)
    STAGE_A(1) STAGE_B(1)
    STAGE_A(2) STAGE_B(2)
    asm volatile("s_waitcnt vmcnt(8)" ::: "memory");
    __builtin_amdgcn_s_barrier();
    asm volatile("" ::: "memory");

    #pragma unroll
    for (int t = 0; t < 32; ++t) {
        const int slot = t & 3;
        f16x8 af[4], bf[4];

        // ---- phase 0: rows wm..wm+63 (acc[0..3]) ----
        #pragma unroll
        for (int j = 0; j < 4; ++j)
            bf[j] = *(const f16x8*)&Bs[slot][(wn + j * 16 + l15) * 32 + (quad ^ rsw) * 8];
        #pragma unroll
        for (int i = 0; i < 4; ++i)
            af[i] = *(const f16x8*)&As[slot][(wm + i * 16 + l15) * 32 + (quad ^ rsw) * 8];
        if (t < 29) STAGE_A(t + 3)
        asm volatile("" ::: "memory");
        __builtin_amdgcn_s_barrier();
        asm volatile("" ::: "memory");
        __builtin_amdgcn_s_setprio(1);
        #pragma unroll
        for (int i = 0; i < 4; ++i)
            #pragma unroll
            for (int j = 0; j < 4; ++j)
                acc[i][j] = __builtin_amdgcn_mfma_f32_16x16x32_f16(af[i], bf[j], acc[i][j], 0, 0, 0);
        __builtin_amdgcn_s_setprio(0);
        asm volatile("" ::: "memory");
        __builtin_amdgcn_s_barrier();
        asm volatile("" ::: "memory");

        // ---- phase 1: rows wm+64..wm+127 (acc[4..7]) ----
        #pragma unroll
        for (int i = 0; i < 4; ++i)
            af[i] = *(const f16x8*)&As[slot][(wm + 64 + i * 16 + l15) * 32 + (quad ^ rsw) * 8];
        if (t < 29) STAGE_B(t + 3)
        asm volatile("" ::: "memory");
        __builtin_amdgcn_s_barrier();
        asm volatile("" ::: "memory");
        __builtin_amdgcn_s_setprio(1);
        #pragma unroll
        for (int i = 0; i < 4; ++i)
            #pragma unroll
            for (int j = 0; j < 4; ++j)
                acc[4 + i][j] = __builtin_amdgcn_mfma_f32_16x16x32_f16(af[i], bf[j], acc[4 + i][j], 0, 0, 0);
        __builtin_amdgcn_s_setprio(0);
        // end-of-tile counted wait: tiles t+2,t+3's 8 loads may stay in
        // flight; tile t+1's data (staged at t-2) is then complete.
        if (t <= 28)      asm volatile("s_waitcnt vmcnt(8)" ::: "memory");
        else if (t == 29) asm volatile("s_waitcnt vmcnt(4)" ::: "memory");
        else if (t == 30) asm volatile("s_waitcnt vmcnt(0)" ::: "memory");
        asm volatile("" ::: "memory");
        __builtin_amdgcn_s_barrier();
        asm volatile("" ::: "memory");
    }
#undef STAGE_A
#undef STAGE_B

    float vf[4];
    #pragma unroll
    for (int j = 0; j < 4; ++j) vf[j] = v[n0 + wn + j * 16 + l15];

    #pragma unroll
    for (int i = 0; i < 8; ++i) {
        #pragma unroll
        for (int r = 0; r < 4; ++r) {
            int m = m0 + wm + i * 16 + quad * 4 + r;   // m = s*32 + b
            int bidx = m & 31;
            float sum = 0.f;
            #pragma unroll
            for (int j = 0; j < 4; ++j) {
                int a = n0 + wn + j * 16 + l15;
                float x = acc[i][j][r] + dp[bidx * A_DIM + a];
                float ex = __expf(2.f * x);
                float th = 1.f - 2.f * __builtin_amdgcn_rcpf(ex + 1.f);
                sum += th * vf[j];
            }
            sum += __shfl_xor(sum, 1);
            sum += __shfl_xor(sum, 2);
            sum += __shfl_xor(sum, 4);
            sum += __shfl_xor(sum, 8);
            if (l15 == 0) atomicAdd(&energy[bidx * S_DIM + (m >> 5)], sum);
        }
    }
}

// one block per b column; energy [B][S] coalesced; noise [S][B] added here
__global__ void scan_alpha_kernel(const float* __restrict__ energy, const float* __restrict__ noise,
                                  float* __restrict__ alpha) {
    __shared__ float sc[256];
    __shared__ float red[256];
    const int b = blockIdx.x;
    const int t = threadIdx.x;
    float p[8], q[8];
    float prod = 1.f;
    #pragma unroll
    for (int k = 0; k < 8; ++k) {
        int s = t * 8 + k;
        float x = energy[b * S_DIM + s] + noise[s * B_DIM + b];
        p[k] = __builtin_amdgcn_rcpf(1.f + __expf(-x));
        q[k] = __builtin_amdgcn_rcpf(1.f + __expf(x));
        prod *= q[k];
    }
    sc[t] = prod;
    __syncthreads();
    for (int off = 1; off < 256; off <<= 1) {
        float mine = sc[t];
        float other = (t >= off) ? sc[t - off] : 1.f;
        __syncthreads();
        sc[t] = mine * other;
        __syncthreads();
    }
    float run = (t > 0) ? sc[t - 1] : 1.f;
    float lsum = 0.f;
    #pragma unroll
    for (int k = 0; k < 8; ++k) {
        int s = t * 8 + k;
        float al = p[k] * run;
        run *= q[k];
        if (s < S_DIM - 1) { alpha[s * B_DIM + b] = al; lsum += al; }
    }
    red[t] = lsum;
    __syncthreads();
    for (int off = 128; off > 0; off >>= 1) {
        if (t < off) red[t] += red[t + off];
        __syncthreads();
    }
    if (t == 0) {
        float tot = fminf(fmaxf(red[0], 0.f), 1.f);
        alpha[(S_DIM - 1) * B_DIM + b] = 1.f - tot;
    }
}

// grid (16 s-chunks, 32 b), block 256: thread t covers e = (t&127)*8..+7 (16B loads),
// halves t<128 / t>=128 split the s range, LDS-reduce, one atomic set per block.
__global__ void wc_kernel(const _Float16* __restrict__ enc, const float* __restrict__ alpha,
                          float* __restrict__ wc) {
    __shared__ float red[128][8];
    const int b = blockIdx.y;
    const int t = threadIdx.x;
    const int e0 = (t & 127) * 8;
    const int half = t >> 7;
    int s = blockIdx.x * 128 + half;
    float acc[8] = {};
    for (int i = 0; i < 64; ++i, s += 2) {
        float al = alpha[s * B_DIM + b];
        f16x8 r = *(const f16x8*)&enc[((size_t)s * B_DIM + b) * E_DIM + e0];
        #pragma unroll
        for (int k = 0; k < 8; ++k) acc[k] += al * (float)r[k];
    }
    if (half) {
        #pragma unroll
        for (int k = 0; k < 8; ++k) red[t - 128][k] = acc[k];
    }
    __syncthreads();
    if (!half) {
        #pragma unroll
        for (int k = 0; k < 8; ++k)
            atomicAdd(&wc[b * E_DIM + e0 + k], acc[k] + red[t][k]);
    }
}

extern "C" void kernel_launch(void* const* d_in, const int* in_sizes, int n_in,
                              void* d_out, int out_size, void* d_ws, size_t ws_size,
                              hipStream_t stream) {
    const float* dec   = (const float*)d_in[0];
    const float* enc   = (const float*)d_in[1];
    const float* noise = (const float*)d_in[2];
    const float* Wd    = (const float*)d_in[3];
    const float* We    = (const float*)d_in[4];
    const float* bias  = (const float*)d_in[5];
    const float* v     = (const float*)d_in[6];

    char* ws = (char*)d_ws;
    _Float16* encf = (_Float16*)(ws + OFF_ENC);
    _Float16* wtf  = (_Float16*)(ws + OFF_WT);
    float* dp      = (float*)(ws + OFF_DP);
    float* energy  = (float*)(ws + OFF_EN);

    float* wc    = (float*)d_out;
    float* alpha = (float*)d_out + B_DIM * E_DIM;

    (void)hipMemsetAsync(wc, 0, B_DIM * E_DIM * sizeof(float), stream);
    (void)hipMemsetAsync(dp, 0, B_DIM * A_DIM * sizeof(float), stream);
    (void)hipMemsetAsync(energy, 0, M_DIM * sizeof(float), stream);

    convert_enc_kernel<<<dim3(M_DIM * E_DIM / 4 / 256), 256, 0, stream>>>((const float4*)enc, (f16x4*)encf);
    transpose_wenc_kernel<<<dim3(32, 32), 256, 0, stream>>>(We, wtf);
    decproj_kernel<<<dim3(16, 4), 256, 0, stream>>>(dec, Wd, bias, dp);
    energy_gemm_kernel<<<dim3(1024), 512, 0, stream>>>(encf, wtf, dp, v, energy);
    scan_alpha_kernel<<<dim3(32), 256, 0, stream>>>(energy, noise, alpha);
    wc_kernel<<<dim3(16, 32), 256, 0, stream>>>(encf, alpha, wc);
}

// Round 4
// 634.359 us; speedup vs baseline: 1.0702x; 1.0090x over previous
//
#include <hip/hip_runtime.h>
#include <hip/hip_fp16.h>

#define S_DIM 2048
#define B_DIM 32
#define E_DIM 1024
#define A_DIM 1024
#define D_DIM 1024
#define M_DIM (S_DIM * B_DIM)  // 65536

typedef _Float16 f16x8 __attribute__((ext_vector_type(8)));
typedef _Float16 f16x4 __attribute__((ext_vector_type(4)));
typedef float f32x4 __attribute__((ext_vector_type(4)));

#define OFF_ENC 0ull
#define OFF_WT  134217728ull
#define OFF_DP  (OFF_WT + 2097152ull)
#define OFF_EN  (OFF_DP + 131072ull)

__device__ inline void load_lds16(const void* g, void* l) {
    __builtin_amdgcn_global_load_lds((const __attribute__((address_space(1))) void*)g,
                                     (__attribute__((address_space(3))) void*)l, 16, 0, 0);
}

__global__ void convert_enc_kernel(const float4* __restrict__ in, f16x4* __restrict__ out) {
    int idx = blockIdx.x * 256 + threadIdx.x;
    float4 f = in[idx];
    f16x4 o = { (_Float16)f.x, (_Float16)f.y, (_Float16)f.z, (_Float16)f.w };
    out[idx] = o;
}

__global__ void transpose_wenc_kernel(const float* __restrict__ W, _Float16* __restrict__ WT) {
    __shared__ _Float16 tile[32][33];
    int a0 = blockIdx.x * 32, e0 = blockIdx.y * 32;
    int tx = threadIdx.x & 31, ty = threadIdx.x >> 5;
    #pragma unroll
    for (int i = 0; i < 32; i += 8)
        tile[ty + i][tx] = (_Float16)W[(size_t)(e0 + ty + i) * A_DIM + a0 + tx];
    __syncthreads();
    #pragma unroll
    for (int i = 0; i < 32; i += 8)
        WT[(size_t)(a0 + ty + i) * E_DIM + e0 + tx] = tile[tx][ty + i];
}

// grid (A/64, 4): block covers 64 a-cols x all 32 b for a 256-wide d-slice.
__global__ void decproj_kernel(const float* __restrict__ dec, const float* __restrict__ Wd,
                               const float* __restrict__ bias, float* __restrict__ dp) {
    const int t = threadIdx.x;
    const int a = blockIdx.x * 64 + (t & 63);
    const int bg = t >> 6;            // 0..3 -> b = bg*8 + bi
    const int d0 = blockIdx.y * 256;
    float acc[8] = {};
    #pragma unroll 4
    for (int d = d0; d < d0 + 256; ++d) {
        float w = Wd[(size_t)d * A_DIM + a];
        #pragma unroll
        for (int bi = 0; bi < 8; ++bi)
            acc[bi] += dec[(size_t)(bg * 8 + bi) * D_DIM + d] * w;
    }
    #pragma unroll
    for (int bi = 0; bi < 8; ++bi) {
        float add = acc[bi] + (blockIdx.y == 0 ? bias[a] : 0.f);
        atomicAdd(&dp[(size_t)(bg * 8 + bi) * A_DIM + a], add);
    }
}

// 256x256 tile, BK=32, 8 waves (2M x 4N, 128x64 per wave).
// 4-deep LDS tile ring (As[4]/Bs[4], 128 KiB), stage distance 3, fully
// unrolled -> compile-time slots. NEW (r4): register double-buffer of
// fragments across the tile boundary -- while tile t's 32 MFMAs run, tile
// t+1's 12 ds_read_b128 are outstanding into the second named frag set
// (counted lgkmcnt lets MFMAs proceed) -> LDS pipe and MFMA pipe overlap.
// ONE barrier per tile (was 4). Counted vmcnt(4) per tile guarantees data
// for t+1 AND t+2 resident at each barrier (reads run one tile ahead).
// Chunk-XOR swizzle (0-conflict, r3-verified): phys 16B chunk p of row r
// holds logical chunk p^((r>>1)&3); staged via XOR on the GLOBAL source
// chunk, read via XOR on the slot.
__global__ __launch_bounds__(512, 2)
void energy_gemm_kernel(const _Float16* __restrict__ Af, const _Float16* __restrict__ Bt,
                        const float* __restrict__ dp, const float* __restrict__ v,
                        float* __restrict__ energy) {
    __shared__ alignas(16) _Float16 As[4][256 * 32];
    __shared__ alignas(16) _Float16 Bs[4][256 * 32];

    const int tid = threadIdx.x;
    const int wid = tid >> 6;
    const int lane = tid & 63;
    const int quad = lane >> 4;
    const int l15 = lane & 15;
    const int rsw = ((l15 >> 1) & 3);   // reader row-XOR term

    // grid = 1024 blocks = 256 m-tiles x 4 n-tiles; bid%8 = XCD (bijective).
    const int bid = blockIdx.x;
    const int xcd = bid & 7;
    const int local = bid >> 3;                 // 0..127
    const int m0 = (xcd * 32 + (local >> 2)) * 256;
    const int n0 = (local & 3) * 256;

    const int wm = (wid >> 2) * 128;            // 0 / 128
    const int wn = (wid & 3) * 64;              // 0..192

    // staging: wave wid covers rows wid*16..+15 and 128+wid*16..+15.
    const int lr = lane >> 2;
    const int lc = ((lane & 3) ^ ((lane >> 3) & 3)) * 8;
    const _Float16* Ag = Af + (size_t)(m0 + wid * 16 + lr) * E_DIM + lc;
    const _Float16* Bg = Bt + (size_t)(n0 + wid * 16 + lr) * E_DIM + lc;

#define STAGE_A(u)                                                              \
    {                                                                           \
        load_lds16(Ag + (size_t)(u) * 32, &As[(u) & 3][wid * 512]);             \
        load_lds16(Ag + (size_t)128 * E_DIM + (size_t)(u) * 32,                 \
                   &As[(u) & 3][(wid + 8) * 512]);                              \
    }
#define STAGE_B(u)                                                              \
    {                                                                           \
        load_lds16(Bg + (size_t)(u) * 32, &Bs[(u) & 3][wid * 512]);             \
        load_lds16(Bg + (size_t)128 * E_DIM + (size_t)(u) * 32,                 \
                   &Bs[(u) & 3][(wid + 8) * 512]);                              \
    }

    f32x4 acc[8][4] = {};
    f16x8 afA[8], bfA[4], afB[8], bfB[4];

    // prologue: tiles 0,1,2 staged (12 loads); vmcnt(4) -> tiles 0 AND 1
    // landed (only STAGE(2)'s 4 newest may fly); barrier; preload frags(0).
    STAGE_A(0) STAGE_B(0)
    STAGE_A(1) STAGE_B(1)
    STAGE_A(2) STAGE_B(2)
    asm volatile("s_waitcnt vmcnt(4)" ::: "memory");
    __builtin_amdgcn_s_barrier();
    asm volatile("" ::: "memory");

    #pragma unroll
    for (int j = 0; j < 4; ++j)
        bfA[j] = *(const f16x8*)&Bs[0][(wn + j * 16 + l15) * 32 + (quad ^ rsw) * 8];
    #pragma unroll
    for (int i = 0; i < 8; ++i)
        afA[i] = *(const f16x8*)&As[0][(wm + i * 16 + l15) * 32 + (quad ^ rsw) * 8];

    // Per tile t: STAGE(t+3); MFMA(t) on CUR set while issuing frags(t+1)
    // into NXT set; vmcnt(4); barrier. Invariant at barrier top of t:
    // data(t), data(t+1) resident; 4 loads (for t+2) in flight; frags(t)
    // issued. Slot (t+3)&3 = (t-1)&3: its readers lgkm-waited before
    // MFMA(t-1), which precedes this tile's barrier.
#define TILE(t, afC, bfC, afN, bfN)                                             \
    {                                                                           \
        if ((t) <= 28) { STAGE_A((t) + 3) STAGE_B((t) + 3) }                    \
        __builtin_amdgcn_s_setprio(1);                                          \
        _Pragma("unroll")                                                       \
        for (int i = 0; i < 8; ++i) {                                           \
            if ((t) < 31 && i < 4)                                              \
                bfN[i] = *(const f16x8*)&Bs[((t) + 1) & 3]                      \
                    [(wn + i * 16 + l15) * 32 + (quad ^ rsw) * 8];              \
            if ((t) < 31)                                                       \
                afN[i] = *(const f16x8*)&As[((t) + 1) & 3]                      \
                    [(wm + i * 16 + l15) * 32 + (quad ^ rsw) * 8];              \
            _Pragma("unroll")                                                   \
            for (int j = 0; j < 4; ++j)                                         \
                acc[i][j] = __builtin_amdgcn_mfma_f32_16x16x32_f16(             \
                    afC[i], bfC[j], acc[i][j], 0, 0, 0);                        \
        }                                                                       \
        __builtin_amdgcn_s_setprio(0);                                          \
        if ((t) <= 28)      asm volatile("s_waitcnt vmcnt(4)" ::: "memory");    \
        else if ((t) == 29) asm volatile("s_waitcnt vmcnt(0)" ::: "memory");    \
        if ((t) < 31) {                                                         \
            asm volatile("" ::: "memory");                                      \
            __builtin_amdgcn_s_barrier();                                       \
            asm volatile("" ::: "memory");                                      \
        }                                                                       \
    }

    #pragma unroll
    for (int tt = 0; tt < 32; tt += 2) {
        TILE(tt,     afA, bfA, afB, bfB)
        TILE(tt + 1, afB, bfB, afA, bfA)
    }
#undef TILE
#undef STAGE_A
#undef STAGE_B

    float vf[4];
    #pragma unroll
    for (int j = 0; j < 4; ++j) vf[j] = v[n0 + wn + j * 16 + l15];

    #pragma unroll
    for (int i = 0; i < 8; ++i) {
        #pragma unroll
        for (int r = 0; r < 4; ++r) {
            int m = m0 + wm + i * 16 + quad * 4 + r;   // m = s*32 + b
            int bidx = m & 31;
            float sum = 0.f;
            #pragma unroll
            for (int j = 0; j < 4; ++j) {
                int a = n0 + wn + j * 16 + l15;
                float x = acc[i][j][r] + dp[bidx * A_DIM + a];
                float ex = __expf(2.f * x);
                float th = 1.f - 2.f * __builtin_amdgcn_rcpf(ex + 1.f);
                sum += th * vf[j];
            }
            sum += __shfl_xor(sum, 1);
            sum += __shfl_xor(sum, 2);
            sum += __shfl_xor(sum, 4);
            sum += __shfl_xor(sum, 8);
            if (l15 == 0) atomicAdd(&energy[bidx * S_DIM + (m >> 5)], sum);
        }
    }
}

// one block per b column; energy [B][S] coalesced; noise [S][B] added here
__global__ void scan_alpha_kernel(const float* __restrict__ energy, const float* __restrict__ noise,
                                  float* __restrict__ alpha) {
    __shared__ float sc[256];
    __shared__ float red[256];
    const int b = blockIdx.x;
    const int t = threadIdx.x;
    float p[8], q[8];
    float prod = 1.f;
    #pragma unroll
    for (int k = 0; k < 8; ++k) {
        int s = t * 8 + k;
        float x = energy[b * S_DIM + s] + noise[s * B_DIM + b];
        p[k] = __builtin_amdgcn_rcpf(1.f + __expf(-x));
        q[k] = __builtin_amdgcn_rcpf(1.f + __expf(x));
        prod *= q[k];
    }
    sc[t] = prod;
    __syncthreads();
    for (int off = 1; off < 256; off <<= 1) {
        float mine = sc[t];
        float other = (t >= off) ? sc[t - off] : 1.f;
        __syncthreads();
        sc[t] = mine * other;
        __syncthreads();
    }
    float run = (t > 0) ? sc[t - 1] : 1.f;
    float lsum = 0.f;
    #pragma unroll
    for (int k = 0; k < 8; ++k) {
        int s = t * 8 + k;
        float al = p[k] * run;
        run *= q[k];
        if (s < S_DIM - 1) { alpha[s * B_DIM + b] = al; lsum += al; }
    }
    red[t] = lsum;
    __syncthreads();
    for (int off = 128; off > 0; off >>= 1) {
        if (t < off) red[t] += red[t + off];
        __syncthreads();
    }
    if (t == 0) {
        float tot = fminf(fmaxf(red[0], 0.f), 1.f);
        alpha[(S_DIM - 1) * B_DIM + b] = 1.f - tot;
    }
}

// grid (16 s-chunks, 32 b), block 256: thread t covers e = (t&127)*8..+7 (16B loads),
// halves t<128 / t>=128 split the s range, LDS-reduce, one atomic set per block.
__global__ void wc_kernel(const _Float16* __restrict__ enc, const float* __restrict__ alpha,
                          float* __restrict__ wc) {
    __shared__ float red[128][8];
    const int b = blockIdx.y;
    const int t = threadIdx.x;
    const int e0 = (t & 127) * 8;
    const int half = t >> 7;
    int s = blockIdx.x * 128 + half;
    float acc[8] = {};
    for (int i = 0; i < 64; ++i, s += 2) {
        float al = alpha[s * B_DIM + b];
        f16x8 r = *(const f16x8*)&enc[((size_t)s * B_DIM + b) * E_DIM + e0];
        #pragma unroll
        for (int k = 0; k < 8; ++k) acc[k] += al * (float)r[k];
    }
    if (half) {
        #pragma unroll
        for (int k = 0; k < 8; ++k) red[t - 128][k] = acc[k];
    }
    __syncthreads();
    if (!half) {
        #pragma unroll
        for (int k = 0; k < 8; ++k)
            atomicAdd(&wc[b * E_DIM + e0 + k], acc[k] + red[t][k]);
    }
}

extern "C" void kernel_launch(void* const* d_in, const int* in_sizes, int n_in,
                              void* d_out, int out_size, void* d_ws, size_t ws_size,
                              hipStream_t stream) {
    const float* dec   = (const float*)d_in[0];
    const float* enc   = (const float*)d_in[1];
    const float* noise = (const float*)d_in[2];
    const float* Wd    = (const float*)d_in[3];
    const float* We    = (const float*)d_in[4];
    const float* bias  = (const float*)d_in[5];
    const float* v     = (const float*)d_in[6];

    char* ws = (char*)d_ws;
    _Float16* encf = (_Float16*)(ws + OFF_ENC);
    _Float16* wtf  = (_Float16*)(ws + OFF_WT);
    float* dp      = (float*)(ws + OFF_DP);
    float* energy  = (float*)(ws + OFF_EN);

    float* wc    = (float*)d_out;
    float* alpha = (float*)d_out + B_DIM * E_DIM;

    (void)hipMemsetAsync(wc, 0, B_DIM * E_DIM * sizeof(float), stream);
    (void)hipMemsetAsync(dp, 0, B_DIM * A_DIM * sizeof(float), stream);
    (void)hipMemsetAsync(energy, 0, M_DIM * sizeof(float), stream);

    convert_enc_kernel<<<dim3(M_DIM * E_DIM / 4 / 256), 256, 0, stream>>>((const float4*)enc, (f16x4*)encf);
    transpose_wenc_kernel<<<dim3(32, 32), 256, 0, stream>>>(We, wtf);
    decproj_kernel<<<dim3(16, 4), 256, 0, stream>>>(dec, Wd, bias, dp);
    energy_gemm_kernel<<<dim3(1024), 512, 0, stream>>>(encf, wtf, dp, v, energy);
    scan_alpha_kernel<<<dim3(32), 256, 0, stream>>>(energy, noise, alpha);
    wc_kernel<<<dim3(16, 32), 256, 0, stream>>>(encf, alpha, wc);
}